// Round 8
// baseline (1633.369 us; speedup 1.0000x reference)
//
#include <hip/hip_runtime.h>

// ---------------------------------------------------------------------------
// GCN graph classifier — deterministic 256-node binning + LDS-accumulate pull.
//   h1 = relu(gcnconv(x, W1, b1));  h2 = relu(gcnconv(h1, W2, b2));
//   g  = mean_pool(h2, batch);      out = g @ Wl + bl
// Premul table: xws[s] = dis[s]*(x@W)[s] (bf16).
//   out[i] = relu( dis[i] * (sum_{e->i} xws[src_e] + xws[i]) + b )
// Edge binning is fully deterministic (hist -> scan -> fill into block-private
// contiguous ranges): no hot atomics, no write-line thrash. Pull accumulates
// each 256-dst bucket in LDS via ds_add_f32 — no per-node CSR needed.
// ---------------------------------------------------------------------------

#define NBLK 256          // histogram / fill blocks (must equal their blockDim)
#define MAXNB 512         // max dst-buckets (n <= 131072)

static __device__ inline ushort f32_to_bf16_rne(float f) {
    uint32_t u = __float_as_uint(f);
    uint32_t r = (u + 0x7fffu + ((u >> 16) & 1u)) >> 16;
    return (ushort)r;
}
static __device__ inline float bf_lo(uint32_t u) { return __uint_as_float(u << 16); }
static __device__ inline float bf_hi(uint32_t u) { return __uint_as_float(u & 0xffff0000u); }

// ---- pass 1: per-block bucket histogram + per-node degree ------------------
__global__ __launch_bounds__(256) void hist_kernel(const int* __restrict__ col,
                                                   int* __restrict__ deg,
                                                   int* __restrict__ hist,
                                                   int E, int NB, int C) {
    __shared__ int cnt[MAXNB];
    for (int i = threadIdx.x; i < NB; i += 256) cnt[i] = 0;
    __syncthreads();
    const int b = blockIdx.x;
    const int e1 = min(b * C + C, E);
    for (int e = b * C + threadIdx.x; e < e1; e += 256) {
        int c = col[e];
        atomicAdd(&cnt[c >> 8], 1);
        atomicAdd(&deg[c], 1);          // low-contention (~16 per address)
    }
    __syncthreads();
    for (int i = threadIdx.x; i < NB; i += 256) hist[b * NB + i] = cnt[i];
}

// ---- dis[i] = rsqrt(deg+1) -------------------------------------------------
__global__ __launch_bounds__(256) void dis_kernel(const int* __restrict__ deg,
                                                  float* __restrict__ dis, int n) {
    int i = blockIdx.x * 256 + threadIdx.x;
    if (i < n) dis[i] = rsqrtf((float)deg[i] + 1.0f);
}

// ---- pass 2a: per-bucket exclusive scan over the 256 blocks (in place) -----
__global__ __launch_bounds__(256) void scan_bucket_kernel(int* __restrict__ hist,
                                                          int* __restrict__ total,
                                                          int NB) {
    __shared__ int sm[256];
    const int k = blockIdx.x;
    int v = hist[threadIdx.x * NB + k];
    sm[threadIdx.x] = v;
    __syncthreads();
    for (int off = 1; off < 256; off <<= 1) {
        int t = (threadIdx.x >= off) ? sm[threadIdx.x - off] : 0;
        __syncthreads();
        sm[threadIdx.x] += t;
        __syncthreads();
    }
    hist[threadIdx.x * NB + k] = sm[threadIdx.x] - v;   // exclusive
    if (threadIdx.x == 255) total[k] = sm[255];
}

// ---- pass 2b: exclusive scan of bucket totals -> start[] -------------------
__global__ __launch_bounds__(512) void start_scan_kernel(const int* __restrict__ total,
                                                         int* __restrict__ start,
                                                         int NB, int E) {
    __shared__ int sm[512];
    int v = (threadIdx.x < NB) ? total[threadIdx.x] : 0;
    sm[threadIdx.x] = v;
    __syncthreads();
    for (int off = 1; off < 512; off <<= 1) {
        int t = (threadIdx.x >= off) ? sm[threadIdx.x - off] : 0;
        __syncthreads();
        sm[threadIdx.x] += t;
        __syncthreads();
    }
    if (threadIdx.x < NB) start[threadIdx.x] = sm[threadIdx.x] - v;
    if (threadIdx.x == 0) start[NB] = E;
}

// ---- pass 3: fill bins; each (block,bucket) range is private+contiguous ----
__global__ __launch_bounds__(256) void fill_bin_kernel(const int* __restrict__ row,
                                                       const int* __restrict__ col,
                                                       const int* __restrict__ hist,
                                                       const int* __restrict__ start,
                                                       int* __restrict__ inter,
                                                       int E, int NB, int C) {
    __shared__ int sbase[MAXNB];
    __shared__ int lcnt[MAXNB];
    const int b = blockIdx.x;
    for (int i = threadIdx.x; i < NB; i += 256) {
        sbase[i] = start[i] + hist[b * NB + i];
        lcnt[i] = 0;
    }
    __syncthreads();
    const int e1 = min(b * C + C, E);
    for (int e = b * C + threadIdx.x; e < e1; e += 256) {
        int r = row[e], c = col[e];
        int k = c >> 8;
        int idx = atomicAdd(&lcnt[k], 1);               // LDS-local only
        inter[sbase[k] + idx] = r | ((c & 255) << 20);  // src<2^20, dstlow 8b
    }
}

// ---- register-tiled GEMM with dis-premul epilogue (f32 or bf16 input) ------
// out_bf16[node][64] = dis[node] * (x[node][K] @ W[K][64])
template <int K, bool BF16IN>
__global__ __launch_bounds__(256) void gemm_tiled(const void* __restrict__ xin,
                                                  const float* __restrict__ W,
                                                  const float* __restrict__ dis,
                                                  ushort* __restrict__ out, int n) {
    __shared__ float As[32][68];     // pad 68: 16B-aligned rows, spread banks
    __shared__ float Ws[32 * 64];
    const int tid = threadIdx.x;
    const int tr = tid >> 4;
    const int tc = tid & 15;
    const int base = blockIdx.x * 64;

    float acc[4][4];
#pragma unroll
    for (int i = 0; i < 4; ++i)
#pragma unroll
        for (int j = 0; j < 4; ++j) acc[i][j] = 0.0f;

    const int tnode = tid >> 3;          // 0..31
    const int tk4 = (tid & 7) * 4;       // 0,4,...,28

    for (int kc = 0; kc < K; kc += 32) {
        __syncthreads();
#pragma unroll
        for (int h = 0; h < 2; ++h) {
            int m = tnode + h * 32;
            int node = base + m;
            float f0 = 0.f, f1 = 0.f, f2 = 0.f, f3 = 0.f;
            if (node < n) {
                if (BF16IN) {
                    const ushort* xb = (const ushort*)xin;
                    uint2 v = *(const uint2*)(xb + (size_t)node * K + kc + tk4);
                    f0 = bf_lo(v.x); f1 = bf_hi(v.x); f2 = bf_lo(v.y); f3 = bf_hi(v.y);
                } else {
                    const float* xf = (const float*)xin;
                    float4 v = *(const float4*)&xf[(size_t)node * K + kc + tk4];
                    f0 = v.x; f1 = v.y; f2 = v.z; f3 = v.w;
                }
            }
            As[tk4 + 0][m] = f0; As[tk4 + 1][m] = f1;
            As[tk4 + 2][m] = f2; As[tk4 + 3][m] = f3;
        }
#pragma unroll
        for (int r = 0; r < 2; ++r) {
            int o = tid * 4 + r * 1024;
            *(float4*)&Ws[o] = *(const float4*)&W[kc * 64 + o];
        }
        __syncthreads();
#pragma unroll
        for (int k = 0; k < 32; ++k) {
            float4 a = *(const float4*)&As[k][tr * 4];
            float4 b = *(const float4*)&Ws[k * 64 + tc * 4];
            const float av[4] = {a.x, a.y, a.z, a.w};
            const float bv[4] = {b.x, b.y, b.z, b.w};
#pragma unroll
            for (int i = 0; i < 4; ++i)
#pragma unroll
                for (int j = 0; j < 4; ++j)
                    acc[i][j] = fmaf(av[i], bv[j], acc[i][j]);
        }
    }
#pragma unroll
    for (int i = 0; i < 4; ++i) {
        int node = base + tr * 4 + i;
        if (node < n) {
            float d = dis[node];
            ushort4 st;
            st.x = f32_to_bf16_rne(acc[i][0] * d);
            st.y = f32_to_bf16_rne(acc[i][1] * d);
            st.z = f32_to_bf16_rne(acc[i][2] * d);
            st.w = f32_to_bf16_rne(acc[i][3] * d);
            *(ushort4*)&out[(size_t)node * 64 + tc * 4] = st;
        }
    }
}

// ---- pull: one block per 256-dst bucket; LDS f32 accumulators --------------
// 4 threads per edge (16 ch each); ds_add_f32; fused self-loop+bias+relu.
#define PAD 65
__global__ __launch_bounds__(256) void gcn_pull_lds(const ushort* __restrict__ xws,
                                                    const int* __restrict__ inter,
                                                    const int* __restrict__ start,
                                                    const float* __restrict__ dis,
                                                    const float* __restrict__ bias,
                                                    ushort* __restrict__ outb, int n) {
    __shared__ float acc[256 * PAD];
    const int tid = threadIdx.x;
    for (int i = tid; i < 256 * PAD; i += 256) acc[i] = 0.0f;
    __syncthreads();
    const int bkt = blockIdx.x;
    const int s = start[bkt], t = start[bkt + 1];
    const int tq = tid & 3, eq = tid >> 2;
    const int chb = tq << 4;             // 16*tq

    int e = s + eq;
    for (; e + 64 < t; e += 128) {       // 2 edges per quad in flight
        int w0 = inter[e], w1 = inter[e + 64];
        int s0 = w0 & 0xFFFFF, s1 = w1 & 0xFFFFF;
        int d0 = (int)(((unsigned)w0) >> 20), d1 = (int)(((unsigned)w1) >> 20);
        const uint4* r0 = (const uint4*)(xws + ((size_t)s0 << 6));
        const uint4* r1 = (const uint4*)(xws + ((size_t)s1 << 6));
        uint4 a0 = r0[tq * 2], b0 = r0[tq * 2 + 1];
        uint4 a1 = r1[tq * 2], b1 = r1[tq * 2 + 1];
        float* A0 = &acc[d0 * PAD + chb];
        atomicAdd(A0 + 0,  bf_lo(a0.x)); atomicAdd(A0 + 1,  bf_hi(a0.x));
        atomicAdd(A0 + 2,  bf_lo(a0.y)); atomicAdd(A0 + 3,  bf_hi(a0.y));
        atomicAdd(A0 + 4,  bf_lo(a0.z)); atomicAdd(A0 + 5,  bf_hi(a0.z));
        atomicAdd(A0 + 6,  bf_lo(a0.w)); atomicAdd(A0 + 7,  bf_hi(a0.w));
        atomicAdd(A0 + 8,  bf_lo(b0.x)); atomicAdd(A0 + 9,  bf_hi(b0.x));
        atomicAdd(A0 + 10, bf_lo(b0.y)); atomicAdd(A0 + 11, bf_hi(b0.y));
        atomicAdd(A0 + 12, bf_lo(b0.z)); atomicAdd(A0 + 13, bf_hi(b0.z));
        atomicAdd(A0 + 14, bf_lo(b0.w)); atomicAdd(A0 + 15, bf_hi(b0.w));
        float* A1 = &acc[d1 * PAD + chb];
        atomicAdd(A1 + 0,  bf_lo(a1.x)); atomicAdd(A1 + 1,  bf_hi(a1.x));
        atomicAdd(A1 + 2,  bf_lo(a1.y)); atomicAdd(A1 + 3,  bf_hi(a1.y));
        atomicAdd(A1 + 4,  bf_lo(a1.z)); atomicAdd(A1 + 5,  bf_hi(a1.z));
        atomicAdd(A1 + 6,  bf_lo(a1.w)); atomicAdd(A1 + 7,  bf_hi(a1.w));
        atomicAdd(A1 + 8,  bf_lo(b1.x)); atomicAdd(A1 + 9,  bf_hi(b1.x));
        atomicAdd(A1 + 10, bf_lo(b1.y)); atomicAdd(A1 + 11, bf_hi(b1.y));
        atomicAdd(A1 + 12, bf_lo(b1.z)); atomicAdd(A1 + 13, bf_hi(b1.z));
        atomicAdd(A1 + 14, bf_lo(b1.w)); atomicAdd(A1 + 15, bf_hi(b1.w));
    }
    for (; e < t; e += 64) {             // tail: 1 edge per quad
        int w0 = inter[e];
        int s0 = w0 & 0xFFFFF;
        int d0 = (int)(((unsigned)w0) >> 20);
        const uint4* r0 = (const uint4*)(xws + ((size_t)s0 << 6));
        uint4 a0 = r0[tq * 2], b0 = r0[tq * 2 + 1];
        float* A0 = &acc[d0 * PAD + chb];
        atomicAdd(A0 + 0,  bf_lo(a0.x)); atomicAdd(A0 + 1,  bf_hi(a0.x));
        atomicAdd(A0 + 2,  bf_lo(a0.y)); atomicAdd(A0 + 3,  bf_hi(a0.y));
        atomicAdd(A0 + 4,  bf_lo(a0.z)); atomicAdd(A0 + 5,  bf_hi(a0.z));
        atomicAdd(A0 + 6,  bf_lo(a0.w)); atomicAdd(A0 + 7,  bf_hi(a0.w));
        atomicAdd(A0 + 8,  bf_lo(b0.x)); atomicAdd(A0 + 9,  bf_hi(b0.x));
        atomicAdd(A0 + 10, bf_lo(b0.y)); atomicAdd(A0 + 11, bf_hi(b0.y));
        atomicAdd(A0 + 12, bf_lo(b0.z)); atomicAdd(A0 + 13, bf_hi(b0.z));
        atomicAdd(A0 + 14, bf_lo(b0.w)); atomicAdd(A0 + 15, bf_hi(b0.w));
    }
    __syncthreads();
    // epilogue: thread-per-node
    const int node = (bkt << 8) + tid;
    if (node < n) {
        const float di = dis[node];
        const uint4* rp = (const uint4*)(xws + ((size_t)node << 6));
        const float* ab = &acc[tid * PAD];
        ushort* op = outb + ((size_t)node << 6);
#pragma unroll
        for (int j = 0; j < 8; ++j) {
            uint4 v = rp[j];
            const int c0 = j * 8;
            float o0 = fmaxf(fmaf(di, ab[c0 + 0] + bf_lo(v.x), bias[c0 + 0]), 0.f);
            float o1 = fmaxf(fmaf(di, ab[c0 + 1] + bf_hi(v.x), bias[c0 + 1]), 0.f);
            float o2 = fmaxf(fmaf(di, ab[c0 + 2] + bf_lo(v.y), bias[c0 + 2]), 0.f);
            float o3 = fmaxf(fmaf(di, ab[c0 + 3] + bf_hi(v.y), bias[c0 + 3]), 0.f);
            float o4 = fmaxf(fmaf(di, ab[c0 + 4] + bf_lo(v.z), bias[c0 + 4]), 0.f);
            float o5 = fmaxf(fmaf(di, ab[c0 + 5] + bf_hi(v.z), bias[c0 + 5]), 0.f);
            float o6 = fmaxf(fmaf(di, ab[c0 + 6] + bf_lo(v.w), bias[c0 + 6]), 0.f);
            float o7 = fmaxf(fmaf(di, ab[c0 + 7] + bf_hi(v.w), bias[c0 + 7]), 0.f);
            uint4 sv;
            sv.x = (uint32_t)f32_to_bf16_rne(o0) | ((uint32_t)f32_to_bf16_rne(o1) << 16);
            sv.y = (uint32_t)f32_to_bf16_rne(o2) | ((uint32_t)f32_to_bf16_rne(o3) << 16);
            sv.z = (uint32_t)f32_to_bf16_rne(o4) | ((uint32_t)f32_to_bf16_rne(o5) << 16);
            sv.w = (uint32_t)f32_to_bf16_rne(o6) | ((uint32_t)f32_to_bf16_rne(o7) << 16);
            *(uint4*)(op + c0) = sv;
        }
    }
}

// ---- segmented mean-pool (batch sorted, bf16 input): 32 nodes/wave ---------
__global__ __launch_bounds__(256) void pool_kernel(const ushort* __restrict__ h,
                                                   const int* __restrict__ batch,
                                                   float* __restrict__ pool,
                                                   float* __restrict__ cnt, int n) {
    const int lane = threadIdx.x & 63;
    const int wid = threadIdx.x >> 6;
    const int startn = (blockIdx.x * 4 + wid) * 32;
    const int endn = min(startn + 32, n);
    if (startn >= endn) return;
    int gcur = batch[startn];
    float acc = 0.0f;
    int c = 0;
    for (int i = startn; i < endn; ++i) {
        int g = batch[i];           // wave-uniform
        if (g != gcur) {
            atomicAdd(&pool[gcur * 64 + lane], acc);
            if (lane == 0) atomicAdd(&cnt[gcur], (float)c);
            acc = 0.0f; c = 0; gcur = g;
        }
        acc += __uint_as_float((uint32_t)h[(size_t)i * 64 + lane] << 16);
        ++c;
    }
    atomicAdd(&pool[gcur * 64 + lane], acc);
    if (lane == 0) atomicAdd(&cnt[gcur], (float)c);
}

// ---- final: out[64][10] = (pool/cnt) @ Wl + bl -----------------------------
__global__ __launch_bounds__(640) void final_kernel(const float* __restrict__ pool,
                                                    const float* __restrict__ cnt,
                                                    const float* __restrict__ Wl,
                                                    const float* __restrict__ bl,
                                                    float* __restrict__ out) {
    int tid = threadIdx.x;            // 640 = 64 graphs * 10 outputs
    int g = tid / 10, o = tid % 10;
    float inv = 1.0f / fmaxf(cnt[g], 1.0f);
    float acc = 0.0f;
#pragma unroll
    for (int l = 0; l < 64; ++l)
        acc = fmaf(pool[g * 64 + l] * inv, Wl[l * 10 + o], acc);
    out[tid] = acc + bl[o];
}

extern "C" void kernel_launch(void* const* d_in, const int* in_sizes, int n_in,
                              void* d_out, int out_size, void* d_ws, size_t ws_size,
                              hipStream_t stream) {
    const float* x  = (const float*)d_in[0];
    const float* W1 = (const float*)d_in[1];
    const float* b1 = (const float*)d_in[2];
    const float* W2 = (const float*)d_in[3];
    const float* b2 = (const float*)d_in[4];
    const float* Wl = (const float*)d_in[5];
    const float* bl = (const float*)d_in[6];
    const int*   ei = (const int*)d_in[7];    // [2, E] -> row = ei, col = ei + E
    const int*   batch = (const int*)d_in[8];
    float* out = (float*)d_out;

    const int n = in_sizes[8];           // 100000 nodes
    const int E = in_sizes[7] / 2;       // 1600000 edges
    const int F = 64;

    const int* row = ei;
    const int* col = ei + E;

    const int NB = (n + 255) >> 8;       // 391 dst-buckets
    const int C  = (E + NBLK - 1) / NBLK;

    // ---- workspace layout (256B-aligned chunks) ----
    char* p = (char*)d_ws;
    auto alloc = [&](size_t bytes) {
        char* r = p;
        p += (bytes + 255) & ~(size_t)255;
        return r;
    };
    int*    degi  = (int*)   alloc((size_t)n * 4);
    float*  dis   = (float*) alloc((size_t)n * 4);
    int*    hist  = (int*)   alloc((size_t)NBLK * MAXNB * 4);  // 512KB
    int*    total = (int*)   alloc(MAXNB * 4);
    int*    startp= (int*)   alloc((MAXNB + 1) * 4);
    int*    inter = (int*)   alloc((size_t)E * 4);             // packed bins
    ushort* xws   = (ushort*)alloc((size_t)n * F * 2);         // bf16 premul table
    ushort* B16   = (ushort*)alloc((size_t)n * F * 2);         // h1 / h2 (bf16)
    float*  pool  = (float*) alloc(64 * 64 * 4);
    float*  cnt   = (float*) alloc(64 * 4);

    const int nb_gemm = (n + 63) / 64;   // 1563

    // ---- binning build (deterministic) ----
    hipMemsetAsync(degi, 0, (size_t)n * 4, stream);
    hist_kernel<<<NBLK, 256, 0, stream>>>(col, degi, hist, E, NB, C);
    scan_bucket_kernel<<<NB, 256, 0, stream>>>(hist, total, NB);
    start_scan_kernel<<<1, 512, 0, stream>>>(total, startp, NB, E);
    dis_kernel<<<(n + 255) / 256, 256, 0, stream>>>(degi, dis, n);
    fill_bin_kernel<<<NBLK, 256, 0, stream>>>(row, col, hist, startp, inter, E, NB, C);

    // ---- layer 1 ----
    gemm_tiled<128, false><<<nb_gemm, 256, 0, stream>>>(x, W1, dis, xws, n);
    gcn_pull_lds<<<NB, 256, 0, stream>>>(xws, inter, startp, dis, b1, B16, n);

    // ---- layer 2 ----
    gemm_tiled<64, true><<<nb_gemm, 256, 0, stream>>>(B16, W2, dis, xws, n);
    gcn_pull_lds<<<NB, 256, 0, stream>>>(xws, inter, startp, dis, b2, B16, n);

    // ---- pool + classifier ----
    hipMemsetAsync(pool, 0, (64 * 64 + 64) * sizeof(float), stream);
    pool_kernel<<<(n + 127) / 128, 256, 0, stream>>>(B16, batch, pool, cnt, n);
    final_kernel<<<1, 640, 0, stream>>>(pool, cnt, Wl, bl, out);
}

// Round 10
// 433.005 us; speedup vs baseline: 3.7722x; 3.7722x over previous
//
#include <hip/hip_runtime.h>

// ---------------------------------------------------------------------------
// GCN graph classifier — proven-component assembly:
//   build: direct atomic CSR fill (src-only payload)       [r4: ~80 µs]
//   layers: premul bf16 table + half-wave/node 8-deep pull [r7 components]
//   out[i] = relu( dis[i] * (sum_{e->i} xws[src_e] + xws[i]) + b )
//   where xws[s] = dis[s] * (x@W)[s] stored bf16.
// ---------------------------------------------------------------------------

static __device__ inline ushort f32_to_bf16_rne(float f) {
    uint32_t u = __float_as_uint(f);
    uint32_t r = (u + 0x7fffu + ((u >> 16) & 1u)) >> 16;
    return (ushort)r;
}
static __device__ inline float bf_lo(uint32_t u) { return __uint_as_float(u << 16); }
static __device__ inline float bf_hi(uint32_t u) { return __uint_as_float(u & 0xffff0000u); }

// ---- degree histogram (int) ------------------------------------------------
__global__ __launch_bounds__(256) void deg_kernel(const int* __restrict__ col,
                                                  int* __restrict__ deg, int E) {
    int e = blockIdx.x * 256 + threadIdx.x;
    if (e < E) atomicAdd(&deg[col[e]], 1);
}

// ---- scan step 1: per-block sums (512 elems/block) -------------------------
__global__ __launch_bounds__(512) void block_sum_kernel(const int* __restrict__ deg,
                                                        int* __restrict__ bsums, int n) {
    __shared__ int sm[512];
    int i = blockIdx.x * 512 + threadIdx.x;
    sm[threadIdx.x] = (i < n) ? deg[i] : 0;
    __syncthreads();
    for (int s = 256; s > 0; s >>= 1) {
        if (threadIdx.x < s) sm[threadIdx.x] += sm[threadIdx.x + s];
        __syncthreads();
    }
    if (threadIdx.x == 0) bsums[blockIdx.x] = sm[0];
}

// ---- scan step 2: exclusive scan of block sums (nb <= 256, one block) ------
__global__ __launch_bounds__(256) void scan_bsums_kernel(int* __restrict__ bsums, int nb) {
    __shared__ int sm[256];
    int v = (threadIdx.x < nb) ? bsums[threadIdx.x] : 0;
    sm[threadIdx.x] = v;
    __syncthreads();
    for (int off = 1; off < 256; off <<= 1) {
        int t = (threadIdx.x >= off) ? sm[threadIdx.x - off] : 0;
        __syncthreads();
        sm[threadIdx.x] += t;
        __syncthreads();
    }
    if (threadIdx.x < nb) bsums[threadIdx.x] = sm[threadIdx.x] - v;  // exclusive
}

// ---- scan step 3: local scan + block offset -> row_ptr; also dis=rsqrt -----
__global__ __launch_bounds__(512) void scan_write_kernel(const int* __restrict__ deg,
                                                         const int* __restrict__ bsums,
                                                         int* __restrict__ rowptr,
                                                         float* __restrict__ dis,
                                                         int n, int E) {
    __shared__ int sm[512];
    int i = blockIdx.x * 512 + threadIdx.x;
    int v = (i < n) ? deg[i] : 0;
    sm[threadIdx.x] = v;
    __syncthreads();
    for (int off = 1; off < 512; off <<= 1) {
        int t = (threadIdx.x >= off) ? sm[threadIdx.x - off] : 0;
        __syncthreads();
        sm[threadIdx.x] += t;
        __syncthreads();
    }
    if (i < n) {
        rowptr[i] = bsums[blockIdx.x] + sm[threadIdx.x] - v;  // exclusive
        dis[i] = rsqrtf((float)v + 1.0f);                     // +1 = self loop
    }
    if (blockIdx.x == 0 && threadIdx.x == 0) rowptr[n] = E;
}

// ---- CSR fill (direct, src-only payload) -----------------------------------
__global__ __launch_bounds__(256) void fill_csr_kernel(const int* __restrict__ row,
                                                       const int* __restrict__ col,
                                                       const int* __restrict__ rowptr,
                                                       int* __restrict__ fill,
                                                       int* __restrict__ csrs, int E) {
    int e = blockIdx.x * 256 + threadIdx.x;
    if (e >= E) return;
    int r = row[e], c = col[e];
    int pos = rowptr[c] + atomicAdd(&fill[c], 1);
    csrs[pos] = r;
}

// ---- register-tiled GEMM with dis-premul epilogue (f32 or bf16 input) ------
// out_bf16[node][64] = dis[node] * (x[node][K] @ W[K][64])
template <int K, bool BF16IN>
__global__ __launch_bounds__(256) void gemm_tiled(const void* __restrict__ xin,
                                                  const float* __restrict__ W,
                                                  const float* __restrict__ dis,
                                                  ushort* __restrict__ out, int n) {
    __shared__ float As[32][68];     // pad 68: 16B-aligned rows, spread banks
    __shared__ float Ws[32 * 64];
    const int tid = threadIdx.x;
    const int tr = tid >> 4;
    const int tc = tid & 15;
    const int base = blockIdx.x * 64;

    float acc[4][4];
#pragma unroll
    for (int i = 0; i < 4; ++i)
#pragma unroll
        for (int j = 0; j < 4; ++j) acc[i][j] = 0.0f;

    const int tnode = tid >> 3;          // 0..31
    const int tk4 = (tid & 7) * 4;       // 0,4,...,28

    for (int kc = 0; kc < K; kc += 32) {
        __syncthreads();
#pragma unroll
        for (int h = 0; h < 2; ++h) {
            int m = tnode + h * 32;
            int node = base + m;
            float f0 = 0.f, f1 = 0.f, f2 = 0.f, f3 = 0.f;
            if (node < n) {
                if (BF16IN) {
                    const ushort* xb = (const ushort*)xin;
                    uint2 v = *(const uint2*)(xb + (size_t)node * K + kc + tk4);
                    f0 = bf_lo(v.x); f1 = bf_hi(v.x); f2 = bf_lo(v.y); f3 = bf_hi(v.y);
                } else {
                    const float* xf = (const float*)xin;
                    float4 v = *(const float4*)&xf[(size_t)node * K + kc + tk4];
                    f0 = v.x; f1 = v.y; f2 = v.z; f3 = v.w;
                }
            }
            As[tk4 + 0][m] = f0; As[tk4 + 1][m] = f1;
            As[tk4 + 2][m] = f2; As[tk4 + 3][m] = f3;
        }
#pragma unroll
        for (int r = 0; r < 2; ++r) {
            int o = tid * 4 + r * 1024;
            *(float4*)&Ws[o] = *(const float4*)&W[kc * 64 + o];
        }
        __syncthreads();
#pragma unroll
        for (int k = 0; k < 32; ++k) {
            float4 a = *(const float4*)&As[k][tr * 4];
            float4 b = *(const float4*)&Ws[k * 64 + tc * 4];
            const float av[4] = {a.x, a.y, a.z, a.w};
            const float bv[4] = {b.x, b.y, b.z, b.w};
#pragma unroll
            for (int i = 0; i < 4; ++i)
#pragma unroll
                for (int j = 0; j < 4; ++j)
                    acc[i][j] = fmaf(av[i], bv[j], acc[i][j]);
        }
    }
#pragma unroll
    for (int i = 0; i < 4; ++i) {
        int node = base + tr * 4 + i;
        if (node < n) {
            float d = dis[node];
            ushort4 st;
            st.x = f32_to_bf16_rne(acc[i][0] * d);
            st.y = f32_to_bf16_rne(acc[i][1] * d);
            st.z = f32_to_bf16_rne(acc[i][2] * d);
            st.w = f32_to_bf16_rne(acc[i][3] * d);
            *(ushort4*)&out[(size_t)node * 64 + tc * 4] = st;
        }
    }
}

// ---- fused pull-aggregate + self-loop + bias + relu ------------------------
// half-wave per dst node (2 nodes/wave); 8-deep gather pipeline; adds only.
// out[i] = relu(dis[i]*(sum xws[src] + xws[i]) + b)   (bf16 out)
__global__ __launch_bounds__(256) void gcn_pull_kernel(const ushort* __restrict__ xws,
                                                       const int* __restrict__ csrs,
                                                       const int* __restrict__ rowptr,
                                                       const float* __restrict__ dis,
                                                       const float* __restrict__ b,
                                                       ushort* __restrict__ outb, int n) {
    const int lane = threadIdx.x & 63;
    const int wv = threadIdx.x >> 6;
    const int half = lane >> 5;          // which node of the pair
    const int q = lane & 31;             // feature pair index
    const float2 bb = ((const float2*)b)[q];

    const int i = (blockIdx.x * 4 + wv) * 2 + half;
    if (i >= n) return;

    const int s = rowptr[i], t = rowptr[i + 1];
    uint32_t us = *(const uint32_t*)(xws + ((size_t)i << 6) + (q << 1));
    float ax = bf_lo(us), ay = bf_hi(us);          // self loop (premul'd)
    int e = s;
    for (; e + 8 <= t; e += 8) {                   // 8 gathers in flight
        int s0 = csrs[e + 0], s1 = csrs[e + 1], s2 = csrs[e + 2], s3 = csrs[e + 3];
        int s4 = csrs[e + 4], s5 = csrs[e + 5], s6 = csrs[e + 6], s7 = csrs[e + 7];
        uint32_t u0 = *(const uint32_t*)(xws + ((size_t)s0 << 6) + (q << 1));
        uint32_t u1 = *(const uint32_t*)(xws + ((size_t)s1 << 6) + (q << 1));
        uint32_t u2 = *(const uint32_t*)(xws + ((size_t)s2 << 6) + (q << 1));
        uint32_t u3 = *(const uint32_t*)(xws + ((size_t)s3 << 6) + (q << 1));
        uint32_t u4 = *(const uint32_t*)(xws + ((size_t)s4 << 6) + (q << 1));
        uint32_t u5 = *(const uint32_t*)(xws + ((size_t)s5 << 6) + (q << 1));
        uint32_t u6 = *(const uint32_t*)(xws + ((size_t)s6 << 6) + (q << 1));
        uint32_t u7 = *(const uint32_t*)(xws + ((size_t)s7 << 6) + (q << 1));
        ax += bf_lo(u0); ay += bf_hi(u0);
        ax += bf_lo(u1); ay += bf_hi(u1);
        ax += bf_lo(u2); ay += bf_hi(u2);
        ax += bf_lo(u3); ay += bf_hi(u3);
        ax += bf_lo(u4); ay += bf_hi(u4);
        ax += bf_lo(u5); ay += bf_hi(u5);
        ax += bf_lo(u6); ay += bf_hi(u6);
        ax += bf_lo(u7); ay += bf_hi(u7);
    }
    for (; e + 2 <= t; e += 2) {
        int s0 = csrs[e], s1 = csrs[e + 1];
        uint32_t u0 = *(const uint32_t*)(xws + ((size_t)s0 << 6) + (q << 1));
        uint32_t u1 = *(const uint32_t*)(xws + ((size_t)s1 << 6) + (q << 1));
        ax += bf_lo(u0); ay += bf_hi(u0);
        ax += bf_lo(u1); ay += bf_hi(u1);
    }
    if (e < t) {
        int s0 = csrs[e];
        uint32_t u0 = *(const uint32_t*)(xws + ((size_t)s0 << 6) + (q << 1));
        ax += bf_lo(u0); ay += bf_hi(u0);
    }
    const float di = dis[i];
    float v0 = fmaxf(fmaf(di, ax, bb.x), 0.0f);
    float v1 = fmaxf(fmaf(di, ay, bb.y), 0.0f);
    ushort2 st = make_ushort2(f32_to_bf16_rne(v0), f32_to_bf16_rne(v1));
    *(ushort2*)(outb + ((size_t)i << 6) + (q << 1)) = st;
}

// ---- segmented mean-pool (batch sorted, bf16 input): 32 nodes/wave ---------
__global__ __launch_bounds__(256) void pool_kernel(const ushort* __restrict__ h,
                                                   const int* __restrict__ batch,
                                                   float* __restrict__ pool,
                                                   float* __restrict__ cnt, int n) {
    const int lane = threadIdx.x & 63;
    const int wid = threadIdx.x >> 6;
    const int startn = (blockIdx.x * 4 + wid) * 32;
    const int endn = min(startn + 32, n);
    if (startn >= endn) return;
    int gcur = batch[startn];
    float acc = 0.0f;
    int c = 0;
    for (int i = startn; i < endn; ++i) {
        int g = batch[i];           // wave-uniform
        if (g != gcur) {
            atomicAdd(&pool[gcur * 64 + lane], acc);
            if (lane == 0) atomicAdd(&cnt[gcur], (float)c);
            acc = 0.0f; c = 0; gcur = g;
        }
        acc += __uint_as_float((uint32_t)h[(size_t)i * 64 + lane] << 16);
        ++c;
    }
    atomicAdd(&pool[gcur * 64 + lane], acc);
    if (lane == 0) atomicAdd(&cnt[gcur], (float)c);
}

// ---- final: out[64][10] = (pool/cnt) @ Wl + bl -----------------------------
__global__ __launch_bounds__(640) void final_kernel(const float* __restrict__ pool,
                                                    const float* __restrict__ cnt,
                                                    const float* __restrict__ Wl,
                                                    const float* __restrict__ bl,
                                                    float* __restrict__ out) {
    int tid = threadIdx.x;            // 640 = 64 graphs * 10 outputs
    int g = tid / 10, o = tid % 10;
    float inv = 1.0f / fmaxf(cnt[g], 1.0f);
    float acc = 0.0f;
#pragma unroll
    for (int l = 0; l < 64; ++l)
        acc = fmaf(pool[g * 64 + l] * inv, Wl[l * 10 + o], acc);
    out[tid] = acc + bl[o];
}

extern "C" void kernel_launch(void* const* d_in, const int* in_sizes, int n_in,
                              void* d_out, int out_size, void* d_ws, size_t ws_size,
                              hipStream_t stream) {
    const float* x  = (const float*)d_in[0];
    const float* W1 = (const float*)d_in[1];
    const float* b1 = (const float*)d_in[2];
    const float* W2 = (const float*)d_in[3];
    const float* b2 = (const float*)d_in[4];
    const float* Wl = (const float*)d_in[5];
    const float* bl = (const float*)d_in[6];
    const int*   ei = (const int*)d_in[7];    // [2, E] -> row = ei, col = ei + E
    const int*   batch = (const int*)d_in[8];
    float* out = (float*)d_out;

    const int n = in_sizes[8];           // 100000 nodes
    const int E = in_sizes[7] / 2;       // 1600000 edges
    const int F = 64;

    const int* row = ei;
    const int* col = ei + E;

    // ---- workspace layout (256B-aligned chunks) ----
    char* p = (char*)d_ws;
    auto alloc = [&](size_t bytes) {
        char* r = p;
        p += (bytes + 255) & ~(size_t)255;
        return r;
    };
    int*    degi   = (int*)   alloc((size_t)n * 4);          // deg, reused as fill
    int*    rowptr = (int*)   alloc((size_t)(n + 1) * 4);
    int*    bsums  = (int*)   alloc(256 * 4);
    float*  dis    = (float*) alloc((size_t)n * 4);
    int*    csrs   = (int*)   alloc((size_t)E * 4);          // src-only CSR
    ushort* xws    = (ushort*)alloc((size_t)n * F * 2);      // bf16 premul table
    ushort* B16    = (ushort*)alloc((size_t)n * F * 2);      // h1 / h2 (bf16)
    float*  pool   = (float*) alloc(64 * 64 * 4);
    float*  cnt    = (float*) alloc(64 * 4);

    const int nb_edge = (E + 255) / 256;
    const int nb_scan = (n + 511) / 512;     // 196 for n=100000
    const int nb_gemm = (n + 63) / 64;       // 1563

    // ---- CSR build (direct fill — best measured variant) ----
    hipMemsetAsync(degi, 0, (size_t)n * 4, stream);
    deg_kernel<<<nb_edge, 256, 0, stream>>>(col, degi, E);
    block_sum_kernel<<<nb_scan, 512, 0, stream>>>(degi, bsums, n);
    scan_bsums_kernel<<<1, 256, 0, stream>>>(bsums, nb_scan);
    scan_write_kernel<<<nb_scan, 512, 0, stream>>>(degi, bsums, rowptr, dis, n, E);
    hipMemsetAsync(degi, 0, (size_t)n * 4, stream);          // reuse as fill counters
    fill_csr_kernel<<<nb_edge, 256, 0, stream>>>(row, col, rowptr, degi, csrs, E);

    // ---- layer 1 ----
    gemm_tiled<128, false><<<nb_gemm, 256, 0, stream>>>(x, W1, dis, xws, n);
    gcn_pull_kernel<<<(n + 7) / 8, 256, 0, stream>>>(xws, csrs, rowptr, dis, b1, B16, n);

    // ---- layer 2 ----
    gemm_tiled<64, true><<<nb_gemm, 256, 0, stream>>>(B16, W2, dis, xws, n);
    gcn_pull_kernel<<<(n + 7) / 8, 256, 0, stream>>>(xws, csrs, rowptr, dis, b2, B16, n);

    // ---- pool + classifier ----
    hipMemsetAsync(pool, 0, (64 * 64 + 64) * sizeof(float), stream);
    pool_kernel<<<(n + 127) / 128, 256, 0, stream>>>(B16, batch, pool, cnt, n);
    final_kernel<<<1, 640, 0, stream>>>(pool, cnt, Wl, bl, out);
}